// Round 2
// baseline (5819.515 us; speedup 1.0000x reference)
//
#include <hip/hip_runtime.h>

#define T_PATCH 256
#define C_DIM   768
#define N_B     8
#define N_N     32

// ---------------- kernel 1: per-(b,n) similarity + matching ----------------
__launch_bounds__(1024, 4)
__global__ void sim_kernel(const float* __restrict__ src_feats,
                           const float* __restrict__ tar_feat,
                           const float* __restrict__ src_masks,
                           const float* __restrict__ tar_mask,
                           float* __restrict__ w_score,
                           float* __restrict__ w_mall,
                           float* __restrict__ w_savg,
                           int*   __restrict__ w_idx,
                           float* __restrict__ out) {
    __shared__ float tarT[2][16][T_PATCH];   // 32 KB
    __shared__ float srcT[2][16][T_PATCH];   // 32 KB
    __shared__ float sq[2048];               // 8 KB
    __shared__ float colv[16 * T_PATCH];     // 16 KB
    __shared__ int   coli[16 * T_PATCH];     // 16 KB
    __shared__ float sc_t2s[T_PATCH];
    __shared__ int   ix_t2s[T_PATCH];
    __shared__ float sc_s2t[T_PATCH];
    __shared__ int   ix_s2t[T_PATCH];
    __shared__ float invT[T_PATCH], invS[T_PATCH], tm[T_PATCH], sm[T_PATCH];
    __shared__ float red[8];

    int bn  = blockIdx.x;
    int b   = bn >> 5;
    int tid = threadIdx.x;
    int tx = tid & 31, ty = tid >> 5;
    int t0 = ty * 8;
    int sA = tx * 4;            // first 4 owned s-columns
    // second 4 owned s-columns: 128 + tx*4
    int r2 = tid >> 7;          // 0..7 -> rows r2, r2+8
    int col2 = (tid & 127) * 2; // even column

    const float* tb = tar_feat + (size_t)b  * C_DIM * T_PATCH;
    const float* sb = src_feats + (size_t)bn * C_DIM * T_PATCH;

    if (tid < T_PATCH) {
        tm[tid] = tar_mask[b * T_PATCH + tid];
        sm[tid] = src_masks[bn * T_PATCH + tid];
    }

    float acc[8][8];
    #pragma unroll
    for (int i = 0; i < 8; ++i)
        #pragma unroll
        for (int j = 0; j < 8; ++j) acc[i][j] = 0.f;

    float2 tss = make_float2(0.f, 0.f);   // per-column tar sum-of-squares
    float2 sss = make_float2(0.f, 0.f);   // per-column src sum-of-squares

    // ---- preload + stage chunk 0
    float2 pt0 = *(const float2*)&tb[r2 * T_PATCH + col2];
    float2 pt1 = *(const float2*)&tb[(r2 + 8) * T_PATCH + col2];
    float2 ps0 = *(const float2*)&sb[r2 * T_PATCH + col2];
    float2 ps1 = *(const float2*)&sb[(r2 + 8) * T_PATCH + col2];
    *(float2*)&tarT[0][r2][col2]     = pt0;
    *(float2*)&tarT[0][r2 + 8][col2] = pt1;
    *(float2*)&srcT[0][r2][col2]     = ps0;
    *(float2*)&srcT[0][r2 + 8][col2] = ps1;
    tss.x = fmaf(pt0.x, pt0.x, fmaf(pt1.x, pt1.x, tss.x));
    tss.y = fmaf(pt0.y, pt0.y, fmaf(pt1.y, pt1.y, tss.y));
    sss.x = fmaf(ps0.x, ps0.x, fmaf(ps1.x, ps1.x, sss.x));
    sss.y = fmaf(ps0.y, ps0.y, fmaf(ps1.y, ps1.y, sss.y));
    __syncthreads();

    int cur = 0;
    for (int c0 = 0; c0 < C_DIM; c0 += 16) {
        int nx = c0 + 16;
        bool more = nx < C_DIM;
        if (more) {
            pt0 = *(const float2*)&tb[(nx + r2) * T_PATCH + col2];
            pt1 = *(const float2*)&tb[(nx + r2 + 8) * T_PATCH + col2];
            ps0 = *(const float2*)&sb[(nx + r2) * T_PATCH + col2];
            ps1 = *(const float2*)&sb[(nx + r2 + 8) * T_PATCH + col2];
        }
        #pragma unroll
        for (int cc = 0; cc < 16; ++cc) {
            float4 a0 = *(const float4*)&tarT[cur][cc][t0];
            float4 a1 = *(const float4*)&tarT[cur][cc][t0 + 4];
            float4 b0 = *(const float4*)&srcT[cur][cc][sA];
            float4 b1 = *(const float4*)&srcT[cur][cc][128 + sA];
            float av[8] = {a0.x, a0.y, a0.z, a0.w, a1.x, a1.y, a1.z, a1.w};
            float bv[8] = {b0.x, b0.y, b0.z, b0.w, b1.x, b1.y, b1.z, b1.w};
            #pragma unroll
            for (int i = 0; i < 8; ++i)
                #pragma unroll
                for (int j = 0; j < 8; ++j)
                    acc[i][j] = fmaf(av[i], bv[j], acc[i][j]);
        }
        if (more) {
            int nb = cur ^ 1;
            *(float2*)&tarT[nb][r2][col2]     = pt0;
            *(float2*)&tarT[nb][r2 + 8][col2] = pt1;
            *(float2*)&srcT[nb][r2][col2]     = ps0;
            *(float2*)&srcT[nb][r2 + 8][col2] = ps1;
            tss.x = fmaf(pt0.x, pt0.x, fmaf(pt1.x, pt1.x, tss.x));
            tss.y = fmaf(pt0.y, pt0.y, fmaf(pt1.y, pt1.y, tss.y));
            sss.x = fmaf(ps0.x, ps0.x, fmaf(ps1.x, ps1.x, sss.x));
            sss.y = fmaf(ps0.y, ps0.y, fmaf(ps1.y, ps1.y, sss.y));
        }
        __syncthreads();
        cur ^= 1;
    }

    // ---- inverse norms (per-column reductions over 8 row-groups)
    sq[r2 * T_PATCH + col2]     = sss.x;
    sq[r2 * T_PATCH + col2 + 1] = sss.y;
    __syncthreads();
    if (tid < T_PATCH) {
        float tot = 0.f;
        #pragma unroll
        for (int g = 0; g < 8; ++g) tot += sq[g * T_PATCH + tid];
        invS[tid] = 1.f / fmaxf(sqrtf(tot), 1e-12f);
    }
    __syncthreads();
    sq[r2 * T_PATCH + col2]     = tss.x;
    sq[r2 * T_PATCH + col2 + 1] = tss.y;
    __syncthreads();
    if (tid < T_PATCH) {
        float tot = 0.f;
        #pragma unroll
        for (int g = 0; g < 8; ++g) tot += sq[g * T_PATCH + tid];
        invT[tid] = 1.f / fmaxf(sqrtf(tot), 1e-12f);
    }
    __syncthreads();

    // ---- normalize + mask + threshold
    #pragma unroll
    for (int i = 0; i < 8; ++i) {
        int t = t0 + i;
        float it = invT[t];
        float mt = tm[t];
        #pragma unroll
        for (int j = 0; j < 8; ++j) {
            int s = (j < 4) ? (sA + j) : (124 + sA + j);
            float v = acc[i][j] * it * invS[s];
            bool keep = (mt != 0.f) && (sm[s] != 0.f) && (v >= 0.05f);
            acc[i][j] = keep ? v : 0.f;
        }
    }

    // ---- t2s: max/argmax over s (rows). Row t spans tx=0..31 (half-wave).
    #pragma unroll
    for (int i = 0; i < 8; ++i) {
        float bv = -1.f; int bi = 0;
        #pragma unroll
        for (int j = 0; j < 8; ++j) {
            float v = acc[i][j];
            int s = (j < 4) ? (sA + j) : (124 + sA + j);
            if (v > bv) { bv = v; bi = s; }
        }
        #pragma unroll
        for (int off = 1; off < 32; off <<= 1) {
            float ov = __shfl_xor(bv, off, 64);
            int   oi = __shfl_xor(bi, off, 64);
            if (ov > bv || (ov == bv && oi < bi)) { bv = ov; bi = oi; }
        }
        if (tx == 0) { sc_t2s[t0 + i] = bv; ix_t2s[t0 + i] = bi; }
    }

    // ---- s2t: max/argmax over t (cols). Combine lane^32 then across waves.
    {
        float cvv[8]; int cvi[8];
        #pragma unroll
        for (int j = 0; j < 8; ++j) {
            float bv = -1.f; int bi = 0;
            #pragma unroll
            for (int i = 0; i < 8; ++i) {
                float v = acc[i][j];
                if (v > bv) { bv = v; bi = t0 + i; }
            }
            float ov = __shfl_xor(bv, 32, 64);
            int   oi = __shfl_xor(bi, 32, 64);
            if (ov > bv || (ov == bv && oi < bi)) { bv = ov; bi = oi; }
            cvv[j] = bv; cvi[j] = bi;
        }
        if ((tid & 63) < 32) {
            int w = tid >> 6;
            #pragma unroll
            for (int j = 0; j < 8; ++j) {
                int s = (j < 4) ? (sA + j) : (124 + sA + j);
                colv[w * T_PATCH + s] = cvv[j];
                coli[w * T_PATCH + s] = cvi[j];
            }
        }
    }
    __syncthreads();
    if (tid < T_PATCH) {
        float bv = -1.f; int bi = 0;
        for (int w = 0; w < 16; ++w) {
            float ov = colv[w * T_PATCH + tid];
            int   oi = coli[w * T_PATCH + tid];
            if (ov > bv || (ov == bv && oi < bi)) { bv = ov; bi = oi; }
        }
        sc_s2t[tid] = bv; ix_s2t[tid] = bi;
    }
    __syncthreads();

    // ---- per-t match decision
    float cnt = 0.f, svs = 0.f;
    if (tid < T_PATCH) {
        int t = tid;
        float st2s = sc_t2s[t];
        int   i    = ix_t2s[t];
        bool msim = st2s >= 0.05f;
        int is2s = ix_s2t[i];
        int dw = (is2s & 15) - (t & 15);
        int dh = (is2s >> 4) - (t >> 4);
        bool cyc = (dw * dw + dh * dh <= 4) && (sc_s2t[i] >= 0.05f);
        float mnz = tm[t] * sm[i] *
                    ((ix_s2t[t] != 0) ? 1.f : 0.f) *
                    ((i != 0) ? 1.f : 0.f);
        float mall = (msim && cyc) ? mnz : 0.f;
        w_score[bn * T_PATCH + t] = st2s;
        w_mall[bn * T_PATCH + t]  = mall;
        w_idx[bn * T_PATCH + t]   = i;
        cnt = mall;
        svs = st2s * mall;
    }
    #pragma unroll
    for (int off = 1; off < 64; off <<= 1) {
        cnt += __shfl_xor(cnt, off, 64);
        svs += __shfl_xor(svs, off, 64);
    }
    if (tid < T_PATCH && (tid & 63) == 0) {
        red[(tid >> 6) * 2]     = cnt;
        red[(tid >> 6) * 2 + 1] = svs;
    }
    __syncthreads();
    if (tid == 0) {
        float c = red[0] + red[2] + red[4] + red[6];
        float s = red[1] + red[3] + red[5] + red[7];
        w_savg[bn] = (c > 0.f) ? (s * (1.f / 256.f)) : 0.f;
        out[51280 + bn] = c;   // match_counts
    }
}

// ---------------- kernel 2: top-k + formatting ----------------
__global__ void final_kernel(const float* __restrict__ w_score,
                             const float* __restrict__ w_mall,
                             const float* __restrict__ w_savg,
                             const int*   __restrict__ w_idx,
                             float* __restrict__ out) {
    int b = blockIdx.x, tid = threadIdx.x;
    __shared__ float savg[32];
    __shared__ int   topid[5];
    __shared__ float topv[5];
    if (tid < 32) savg[tid] = w_savg[b * 32 + tid];
    __syncthreads();
    if (tid == 0) {
        unsigned used = 0;
        for (int k = 0; k < 5; ++k) {
            float bv = -1e30f; int bi = 0;
            for (int n = 0; n < 32; ++n) {
                if (!((used >> n) & 1u) && savg[n] > bv) { bv = savg[n]; bi = n; }
            }
            used |= (1u << bi);
            topid[k] = bi; topv[k] = bv;
        }
    }
    __syncthreads();
    if (tid < 5) {
        out[b * 5 + tid]      = (float)topid[tid];   // id_src
        out[40 + b * 5 + tid] = topv[tid];           // score_src
    }
    int t = tid;
    for (int k = 0; k < 5; ++k) {
        int bn = b * 32 + topid[k];
        float sc = w_score[bn * 256 + t];
        float ma = w_mall[bn * 256 + t];
        int   ii = w_idx[bn * 256 + t];
        int o = (b * 5 + k) * 256 + t;
        out[80 + o] = sc;                            // score_pts
        bool nz = (ma != 0.f);
        out[10320 + 2 * o]     = nz ? (float)(t & 15)  : -1.f;  // tar_pts w
        out[10320 + 2 * o + 1] = nz ? (float)(t >> 4)  : -1.f;  // tar_pts h
        out[30800 + 2 * o]     = nz ? (float)(ii & 15) : -1.f;  // src_pts w
        out[30800 + 2 * o + 1] = nz ? (float)(ii >> 4) : -1.f;  // src_pts h
    }
}

extern "C" void kernel_launch(void* const* d_in, const int* in_sizes, int n_in,
                              void* d_out, int out_size, void* d_ws, size_t ws_size,
                              hipStream_t stream) {
    const float* src_feats = (const float*)d_in[0];
    const float* tar_feat  = (const float*)d_in[1];
    const float* src_masks = (const float*)d_in[2];
    const float* tar_mask  = (const float*)d_in[3];
    float* out = (float*)d_out;

    float* ws      = (float*)d_ws;
    float* w_score = ws;                        // 65536
    float* w_mall  = w_score + 65536;           // 65536
    float* w_savg  = w_mall + 65536;            // 256
    int*   w_idx   = (int*)(w_savg + 256);      // 65536

    sim_kernel<<<N_B * N_N, 1024, 0, stream>>>(src_feats, tar_feat, src_masks,
                                               tar_mask,
                                               w_score, w_mall, w_savg, w_idx, out);
    final_kernel<<<N_B, 256, 0, stream>>>(w_score, w_mall, w_savg, w_idx, out);
}

// Round 3
// 499.013 us; speedup vs baseline: 11.6620x; 11.6620x over previous
//
#include <hip/hip_runtime.h>

#define T_PATCH 256
#define C_DIM   768
#define N_B     8
#define N_N     32

// ---------------- kernel 1: per-(b,n) similarity + matching ----------------
// NOTE: 1024-thread block = 16 waves => HARD cap 128 regs/wave (unified
// VGPR+AGPR). acc[8][8] lives in AGPRs (64) + ~60 VGPRs. Round-2 post-mortem:
// adding live prefetch registers across the FMA loop spills acc to scratch
// (12 GB of WRITE_SIZE). Do NOT hold loaded values across the compute loop.
__launch_bounds__(1024, 4)
__global__ void sim_kernel(const float* __restrict__ src_feats,
                           const float* __restrict__ tar_feat,
                           const float* __restrict__ src_masks,
                           const float* __restrict__ tar_mask,
                           float* __restrict__ w_score,
                           float* __restrict__ w_mall,
                           float* __restrict__ w_savg,
                           int*   __restrict__ w_idx,
                           float* __restrict__ out) {
    __shared__ float tarT[16][T_PATCH];    // 16 KB
    __shared__ float srcT[16][T_PATCH];    // 16 KB
    __shared__ float sq[2048];             // 8 KB
    __shared__ float colv[16 * T_PATCH];   // 16 KB
    __shared__ int   coli[16 * T_PATCH];   // 16 KB
    __shared__ float sc_t2s[T_PATCH];
    __shared__ int   ix_t2s[T_PATCH];
    __shared__ float sc_s2t[T_PATCH];
    __shared__ int   ix_s2t[T_PATCH];
    __shared__ float invT[T_PATCH], invS[T_PATCH], tm[T_PATCH], sm[T_PATCH];
    __shared__ float red[8];

    int bn  = blockIdx.x;
    int b   = bn >> 5;
    int tid = threadIdx.x;
    int tx = tid & 31, ty = tid >> 5;
    int t0 = ty * 8;
    int sA = tx * 4;            // owned s-columns: sA..sA+3 and 128+sA..+3
    int r2 = tid >> 7;          // 0..7 -> rows r2, r2+8 of the chunk
    int col2 = (tid & 127) * 2; // even column

    const float* tb = tar_feat + (size_t)b  * C_DIM * T_PATCH;
    const float* sb = src_feats + (size_t)bn * C_DIM * T_PATCH;

    if (tid < T_PATCH) {
        tm[tid] = tar_mask[b * T_PATCH + tid];
        sm[tid] = src_masks[bn * T_PATCH + tid];
    }

    float acc[8][8];
    #pragma unroll
    for (int i = 0; i < 8; ++i)
        #pragma unroll
        for (int j = 0; j < 8; ++j) acc[i][j] = 0.f;

    float2 tss = make_float2(0.f, 0.f);   // per-column tar sum-of-squares
    float2 sss = make_float2(0.f, 0.f);   // per-column src sum-of-squares

    for (int c0 = 0; c0 < C_DIM; c0 += 16) {
        // loads issue here; their latency overlaps the barrier wait
        float2 pt0 = *(const float2*)&tb[(c0 + r2) * T_PATCH + col2];
        float2 pt1 = *(const float2*)&tb[(c0 + r2 + 8) * T_PATCH + col2];
        float2 ps0 = *(const float2*)&sb[(c0 + r2) * T_PATCH + col2];
        float2 ps1 = *(const float2*)&sb[(c0 + r2 + 8) * T_PATCH + col2];
        __syncthreads();   // previous compute done before overwrite
        *(float2*)&tarT[r2][col2]     = pt0;
        *(float2*)&tarT[r2 + 8][col2] = pt1;
        *(float2*)&srcT[r2][col2]     = ps0;
        *(float2*)&srcT[r2 + 8][col2] = ps1;
        tss.x = fmaf(pt0.x, pt0.x, fmaf(pt1.x, pt1.x, tss.x));
        tss.y = fmaf(pt0.y, pt0.y, fmaf(pt1.y, pt1.y, tss.y));
        sss.x = fmaf(ps0.x, ps0.x, fmaf(ps1.x, ps1.x, sss.x));
        sss.y = fmaf(ps0.y, ps0.y, fmaf(ps1.y, ps1.y, sss.y));
        __syncthreads();
        #pragma unroll
        for (int cc = 0; cc < 16; ++cc) {
            float4 a0 = *(const float4*)&tarT[cc][t0];
            float4 a1 = *(const float4*)&tarT[cc][t0 + 4];
            float4 b0 = *(const float4*)&srcT[cc][sA];
            float4 b1 = *(const float4*)&srcT[cc][128 + sA];
            float av[8] = {a0.x, a0.y, a0.z, a0.w, a1.x, a1.y, a1.z, a1.w};
            float bv[8] = {b0.x, b0.y, b0.z, b0.w, b1.x, b1.y, b1.z, b1.w};
            #pragma unroll
            for (int i = 0; i < 8; ++i)
                #pragma unroll
                for (int j = 0; j < 8; ++j)
                    acc[i][j] = fmaf(av[i], bv[j], acc[i][j]);
        }
    }

    // ---- inverse norms (per-column reduction over 8 row-groups)
    __syncthreads();
    sq[r2 * T_PATCH + col2]     = sss.x;
    sq[r2 * T_PATCH + col2 + 1] = sss.y;
    __syncthreads();
    if (tid < T_PATCH) {
        float tot = 0.f;
        #pragma unroll
        for (int g = 0; g < 8; ++g) tot += sq[g * T_PATCH + tid];
        invS[tid] = 1.f / fmaxf(sqrtf(tot), 1e-12f);
    }
    __syncthreads();
    sq[r2 * T_PATCH + col2]     = tss.x;
    sq[r2 * T_PATCH + col2 + 1] = tss.y;
    __syncthreads();
    if (tid < T_PATCH) {
        float tot = 0.f;
        #pragma unroll
        for (int g = 0; g < 8; ++g) tot += sq[g * T_PATCH + tid];
        invT[tid] = 1.f / fmaxf(sqrtf(tot), 1e-12f);
    }
    __syncthreads();

    // ---- normalize + mask + threshold
    #pragma unroll
    for (int i = 0; i < 8; ++i) {
        int t = t0 + i;
        float it = invT[t];
        float mt = tm[t];
        #pragma unroll
        for (int j = 0; j < 8; ++j) {
            int s = (j < 4) ? (sA + j) : (124 + sA + j);
            float v = acc[i][j] * it * invS[s];
            bool keep = (mt != 0.f) && (sm[s] != 0.f) && (v >= 0.05f);
            acc[i][j] = keep ? v : 0.f;
        }
    }

    // ---- t2s: max/argmax over s (rows). Row t spans tx=0..31 (half-wave).
    #pragma unroll
    for (int i = 0; i < 8; ++i) {
        float bv = -1.f; int bi = 0;
        #pragma unroll
        for (int j = 0; j < 8; ++j) {
            float v = acc[i][j];
            int s = (j < 4) ? (sA + j) : (124 + sA + j);
            if (v > bv) { bv = v; bi = s; }
        }
        #pragma unroll
        for (int off = 1; off < 32; off <<= 1) {
            float ov = __shfl_xor(bv, off, 64);
            int   oi = __shfl_xor(bi, off, 64);
            if (ov > bv || (ov == bv && oi < bi)) { bv = ov; bi = oi; }
        }
        if (tx == 0) { sc_t2s[t0 + i] = bv; ix_t2s[t0 + i] = bi; }
    }

    // ---- s2t: max/argmax over t (cols). Combine lane^32 then across waves.
    {
        float cvv[8]; int cvi[8];
        #pragma unroll
        for (int j = 0; j < 8; ++j) {
            float bv = -1.f; int bi = 0;
            #pragma unroll
            for (int i = 0; i < 8; ++i) {
                float v = acc[i][j];
                if (v > bv) { bv = v; bi = t0 + i; }
            }
            float ov = __shfl_xor(bv, 32, 64);
            int   oi = __shfl_xor(bi, 32, 64);
            if (ov > bv || (ov == bv && oi < bi)) { bv = ov; bi = oi; }
            cvv[j] = bv; cvi[j] = bi;
        }
        if ((tid & 63) < 32) {
            int w = tid >> 6;
            #pragma unroll
            for (int j = 0; j < 8; ++j) {
                int s = (j < 4) ? (sA + j) : (124 + sA + j);
                colv[w * T_PATCH + s] = cvv[j];
                coli[w * T_PATCH + s] = cvi[j];
            }
        }
    }
    __syncthreads();
    if (tid < T_PATCH) {
        float bv = -1.f; int bi = 0;
        for (int w = 0; w < 16; ++w) {
            float ov = colv[w * T_PATCH + tid];
            int   oi = coli[w * T_PATCH + tid];
            if (ov > bv || (ov == bv && oi < bi)) { bv = ov; bi = oi; }
        }
        sc_s2t[tid] = bv; ix_s2t[tid] = bi;
    }
    __syncthreads();

    // ---- per-t match decision
    float cnt = 0.f, svs = 0.f;
    if (tid < T_PATCH) {
        int t = tid;
        float st2s = sc_t2s[t];
        int   i    = ix_t2s[t];
        bool msim = st2s >= 0.05f;
        int is2s = ix_s2t[i];
        int dw = (is2s & 15) - (t & 15);
        int dh = (is2s >> 4) - (t >> 4);
        bool cyc = (dw * dw + dh * dh <= 4) && (sc_s2t[i] >= 0.05f);
        float mnz = tm[t] * sm[i] *
                    ((ix_s2t[t] != 0) ? 1.f : 0.f) *
                    ((i != 0) ? 1.f : 0.f);
        float mall = (msim && cyc) ? mnz : 0.f;
        w_score[bn * T_PATCH + t] = st2s;
        w_mall[bn * T_PATCH + t]  = mall;
        w_idx[bn * T_PATCH + t]   = i;
        cnt = mall;
        svs = st2s * mall;
    }
    #pragma unroll
    for (int off = 1; off < 64; off <<= 1) {
        cnt += __shfl_xor(cnt, off, 64);
        svs += __shfl_xor(svs, off, 64);
    }
    if (tid < T_PATCH && (tid & 63) == 0) {
        red[(tid >> 6) * 2]     = cnt;
        red[(tid >> 6) * 2 + 1] = svs;
    }
    __syncthreads();
    if (tid == 0) {
        float c = red[0] + red[2] + red[4] + red[6];
        float s = red[1] + red[3] + red[5] + red[7];
        w_savg[bn] = (c > 0.f) ? (s * (1.f / 256.f)) : 0.f;
        out[51280 + bn] = c;   // match_counts
    }
}

// ---------------- kernel 2: top-k + formatting ----------------
__global__ void final_kernel(const float* __restrict__ w_score,
                             const float* __restrict__ w_mall,
                             const float* __restrict__ w_savg,
                             const int*   __restrict__ w_idx,
                             float* __restrict__ out) {
    int b = blockIdx.x, tid = threadIdx.x;
    __shared__ float savg[32];
    __shared__ int   topid[5];
    __shared__ float topv[5];
    if (tid < 32) savg[tid] = w_savg[b * 32 + tid];
    __syncthreads();
    if (tid == 0) {
        unsigned used = 0;
        for (int k = 0; k < 5; ++k) {
            float bv = -1e30f; int bi = 0;
            for (int n = 0; n < 32; ++n) {
                if (!((used >> n) & 1u) && savg[n] > bv) { bv = savg[n]; bi = n; }
            }
            used |= (1u << bi);
            topid[k] = bi; topv[k] = bv;
        }
    }
    __syncthreads();
    if (tid < 5) {
        out[b * 5 + tid]      = (float)topid[tid];   // id_src
        out[40 + b * 5 + tid] = topv[tid];           // score_src
    }
    int t = tid;
    for (int k = 0; k < 5; ++k) {
        int bn = b * 32 + topid[k];
        float sc = w_score[bn * 256 + t];
        float ma = w_mall[bn * 256 + t];
        int   ii = w_idx[bn * 256 + t];
        int o = (b * 5 + k) * 256 + t;
        out[80 + o] = sc;                            // score_pts
        bool nz = (ma != 0.f);
        out[10320 + 2 * o]     = nz ? (float)(t & 15)  : -1.f;  // tar_pts w
        out[10320 + 2 * o + 1] = nz ? (float)(t >> 4)  : -1.f;  // tar_pts h
        out[30800 + 2 * o]     = nz ? (float)(ii & 15) : -1.f;  // src_pts w
        out[30800 + 2 * o + 1] = nz ? (float)(ii >> 4) : -1.f;  // src_pts h
    }
}

extern "C" void kernel_launch(void* const* d_in, const int* in_sizes, int n_in,
                              void* d_out, int out_size, void* d_ws, size_t ws_size,
                              hipStream_t stream) {
    const float* src_feats = (const float*)d_in[0];
    const float* tar_feat  = (const float*)d_in[1];
    const float* src_masks = (const float*)d_in[2];
    const float* tar_mask  = (const float*)d_in[3];
    float* out = (float*)d_out;

    float* ws      = (float*)d_ws;
    float* w_score = ws;                        // 65536
    float* w_mall  = w_score + 65536;           // 65536
    float* w_savg  = w_mall + 65536;            // 256
    int*   w_idx   = (int*)(w_savg + 256);      // 65536

    sim_kernel<<<N_B * N_N, 1024, 0, stream>>>(src_feats, tar_feat, src_masks,
                                               tar_mask,
                                               w_score, w_mall, w_savg, w_idx, out);
    final_kernel<<<N_B, 256, 0, stream>>>(w_score, w_mall, w_savg, w_idx, out);
}

// Round 5
// 371.683 us; speedup vs baseline: 15.6572x; 1.3426x over previous
//
#include <hip/hip_runtime.h>

#define T_PATCH 256
#define C_DIM   768
#define N_B     8
#define N_N     32

typedef unsigned short u16;
typedef u16   u16x8  __attribute__((ext_vector_type(8)));
typedef short s16x8  __attribute__((ext_vector_type(8)));
typedef float f32x16 __attribute__((ext_vector_type(16)));

__device__ __forceinline__ unsigned rne16(unsigned u) {
    // fp32 bits -> bf16 bits, round-to-nearest-even
    return (u + 0x7fffu + ((u >> 16) & 1u)) >> 16;
}

// ---------------- kernel 1: per-(b,n) similarity + matching ----------------
// 3-way RNE bf16 split MFMA: x = x0 + x1 + x2 (|x1|<=2^-8|x|, |x2|<=2^-16|x|).
// dot via 6 MFMAs: 00,01,10,11,02,20 -> cosine error ~2e-9 (< fp32 reorder noise).
// Round-2 lesson: 512 thr => 256 reg cap; acc(128)+frags+prefetch ~230. Watch WRITE_SIZE.
__launch_bounds__(512, 2)
__global__ void sim_kernel(const float* __restrict__ src_feats,
                           const float* __restrict__ tar_feat,
                           const float* __restrict__ src_masks,
                           const float* __restrict__ tar_mask,
                           float* __restrict__ w_score,
                           float* __restrict__ w_mall,
                           float* __restrict__ w_savg,
                           int*   __restrict__ w_idx,
                           float* __restrict__ out) {
    // staging: [buf][g][t][8] bf16, g = k-group of 8  (16 KB each, 96 KB total)
    __shared__ __align__(16) u16 A0[2][2][256][8];
    __shared__ __align__(16) u16 A1[2][2][256][8];
    __shared__ __align__(16) u16 A2[2][2][256][8];
    __shared__ __align__(16) u16 B0[2][2][256][8];
    __shared__ __align__(16) u16 B1[2][2][256][8];
    __shared__ __align__(16) u16 B2[2][2][256][8];
    __shared__ float sqT[512], sqS[512];
    __shared__ float rowv[2][256];  __shared__ int rowi[2][256];
    __shared__ float colv[4][256];  __shared__ int coli[4][256];
    __shared__ float sc_t2s[256];   __shared__ int ix_t2s[256];
    __shared__ float sc_s2t[256];   __shared__ int ix_s2t[256];
    __shared__ float invT[256], invS[256], tm[256], sm[256];
    __shared__ float red[8];

    int bn  = blockIdx.x;
    int b   = bn >> 5;
    int tid = threadIdx.x;
    int lane = tid & 63, w = tid >> 6;       // 8 waves
    int wm = w >> 1, wn = w & 1;             // 4 m-groups x 2 n-groups
    int h = lane >> 5, l5 = lane & 31;
    int tS = tid & 255, g = tid >> 8;        // staging slot (t, k-group)

    const float* tb = tar_feat + (size_t)b  * C_DIM * T_PATCH;
    const float* sb = src_feats + (size_t)bn * C_DIM * T_PATCH;

    if (tid < 256) {
        tm[tid] = tar_mask[b * T_PATCH + tid];
        sm[tid] = src_masks[bn * T_PATCH + tid];
    }

    f32x16 acc[2][4];
    #pragma unroll
    for (int i = 0; i < 2; ++i)
        #pragma unroll
        for (int j = 0; j < 4; ++j) acc[i][j] = (f32x16)0.0f;

    float tss = 0.f, sss = 0.f;
    float xv[8], yv[8];
    #pragma unroll
    for (int j = 0; j < 8; ++j) {
        xv[j] = tb[(g * 8 + j) * T_PATCH + tS];
        yv[j] = sb[(g * 8 + j) * T_PATCH + tS];
    }

    int buf = 0;
    for (int c0 = 0; c0 < C_DIM; c0 += 16, buf ^= 1) {
        __syncthreads();   // waves finished reading this buf
        u16x8 t0v, t1v, t2v, s0v, s1v, s2v;
        #pragma unroll
        for (int j = 0; j < 8; ++j) {
            float x = xv[j];
            unsigned u0 = rne16(__float_as_uint(x));
            float f0 = __uint_as_float(u0 << 16);
            float r1 = x - f0;
            unsigned u1 = rne16(__float_as_uint(r1));
            float f1 = __uint_as_float(u1 << 16);
            float r2 = r1 - f1;
            t0v[j] = (u16)u0;
            t1v[j] = (u16)u1;
            t2v[j] = (u16)(__float_as_uint(r2) >> 16);
            tss = fmaf(x, x, tss);
            float y = yv[j];
            unsigned v0 = rne16(__float_as_uint(y));
            float g0 = __uint_as_float(v0 << 16);
            float q1 = y - g0;
            unsigned v1 = rne16(__float_as_uint(q1));
            float g1 = __uint_as_float(v1 << 16);
            float q2 = q1 - g1;
            s0v[j] = (u16)v0;
            s1v[j] = (u16)v1;
            s2v[j] = (u16)(__float_as_uint(q2) >> 16);
            sss = fmaf(y, y, sss);
        }
        *(u16x8*)&A0[buf][g][tS][0] = t0v;
        *(u16x8*)&A1[buf][g][tS][0] = t1v;
        *(u16x8*)&A2[buf][g][tS][0] = t2v;
        *(u16x8*)&B0[buf][g][tS][0] = s0v;
        *(u16x8*)&B1[buf][g][tS][0] = s1v;
        *(u16x8*)&B2[buf][g][tS][0] = s2v;
        int c1 = c0 + 16;
        if (c1 < C_DIM) {
            #pragma unroll
            for (int j = 0; j < 8; ++j) {
                xv[j] = tb[(c1 + g * 8 + j) * T_PATCH + tS];
                yv[j] = sb[(c1 + g * 8 + j) * T_PATCH + tS];
            }
        }
        __syncthreads();   // staging visible
        // A-frag: lane -> A[m = l5][k = h*8+j]   (validated in round 4)
        s16x8 a0[2], a1[2], a2[2];
        #pragma unroll
        for (int i = 0; i < 2; ++i) {
            int row = wm * 64 + i * 32 + l5;
            a0[i] = *(const s16x8*)&A0[buf][h][row][0];
            a1[i] = *(const s16x8*)&A1[buf][h][row][0];
            a2[i] = *(const s16x8*)&A2[buf][h][row][0];
        }
        #pragma unroll
        for (int j = 0; j < 4; ++j) {
            int col = wn * 128 + j * 32 + l5;
            s16x8 b0 = *(const s16x8*)&B0[buf][h][col][0];
            s16x8 b1 = *(const s16x8*)&B1[buf][h][col][0];
            s16x8 b2 = *(const s16x8*)&B2[buf][h][col][0];
            #pragma unroll
            for (int i = 0; i < 2; ++i) {
                acc[i][j] = __builtin_amdgcn_mfma_f32_32x32x16_bf16(a0[i], b0, acc[i][j], 0, 0, 0);
                acc[i][j] = __builtin_amdgcn_mfma_f32_32x32x16_bf16(a0[i], b1, acc[i][j], 0, 0, 0);
                acc[i][j] = __builtin_amdgcn_mfma_f32_32x32x16_bf16(a1[i], b0, acc[i][j], 0, 0, 0);
                acc[i][j] = __builtin_amdgcn_mfma_f32_32x32x16_bf16(a1[i], b1, acc[i][j], 0, 0, 0);
                acc[i][j] = __builtin_amdgcn_mfma_f32_32x32x16_bf16(a0[i], b2, acc[i][j], 0, 0, 0);
                acc[i][j] = __builtin_amdgcn_mfma_f32_32x32x16_bf16(a2[i], b0, acc[i][j], 0, 0, 0);
            }
        }
    }

    // ---- norms (masks folded into inverse norms; sm kept separately for mnz)
    sqT[g * 256 + tS] = tss;
    sqS[g * 256 + tS] = sss;
    __syncthreads();
    if (tid < 256) {
        float nt = sqrtf(sqT[tid] + sqT[256 + tid]);
        invT[tid] = (tm[tid] != 0.f) ? 1.f / fmaxf(nt, 1e-12f) : 0.f;
        float ns = sqrtf(sqS[tid] + sqS[256 + tid]);
        invS[tid] = (sm[tid] != 0.f) ? 1.f / fmaxf(ns, 1e-12f) : 0.f;
    }
    __syncthreads();

    // ---- normalize + threshold + row/col argmax
    // C/D layout: col = l5, row = (reg&3) + 8*(reg>>2) + 4*h   [m74/m101]
    float isv[4];
    #pragma unroll
    for (int j = 0; j < 4; ++j) isv[j] = invS[wn * 128 + j * 32 + l5];

    float cbv[4]; int cbi[4];
    #pragma unroll
    for (int j = 0; j < 4; ++j) { cbv[j] = -1.f; cbi[j] = 0; }

    #pragma unroll
    for (int i = 0; i < 2; ++i) {
        #pragma unroll
        for (int r = 0; r < 16; ++r) {
            int trow = wm * 64 + i * 32 + (r & 3) + 8 * (r >> 2) + 4 * h;
            float it = invT[trow];   // broadcast read
            float v[4];
            #pragma unroll
            for (int j = 0; j < 4; ++j) {
                float x = acc[i][j][r] * it * isv[j];
                v[j] = (x >= 0.05f) ? x : 0.f;
            }
            float bv = -1.f; int bi = 0;
            #pragma unroll
            for (int j = 0; j < 4; ++j) {
                int s = wn * 128 + j * 32 + l5;
                if (v[j] > bv) { bv = v[j]; bi = s; }
            }
            #pragma unroll
            for (int off = 1; off < 32; off <<= 1) {
                float ov = __shfl_xor(bv, off, 64);
                int   oi = __shfl_xor(bi, off, 64);
                if (ov > bv || (ov == bv && oi < bi)) { bv = ov; bi = oi; }
            }
            if (l5 == 0) { rowv[wn][trow] = bv; rowi[wn][trow] = bi; }
            #pragma unroll
            for (int j = 0; j < 4; ++j) {
                if (v[j] > cbv[j]) { cbv[j] = v[j]; cbi[j] = trow; }
            }
        }
    }
    #pragma unroll
    for (int j = 0; j < 4; ++j) {
        float bv = cbv[j]; int bi = cbi[j];
        float ov = __shfl_xor(bv, 32, 64);
        int   oi = __shfl_xor(bi, 32, 64);
        if (ov > bv || (ov == bv && oi < bi)) { bv = ov; bi = oi; }
        if (h == 0) { colv[wm][wn * 128 + j * 32 + l5] = bv; coli[wm][wn * 128 + j * 32 + l5] = bi; }
    }
    __syncthreads();
    if (tid < 256) {
        float bv = rowv[0][tid]; int bi = rowi[0][tid];
        float ov = rowv[1][tid]; int oi = rowi[1][tid];
        if (ov > bv || (ov == bv && oi < bi)) { bv = ov; bi = oi; }
        sc_t2s[tid] = bv; ix_t2s[tid] = bi;
        bv = colv[0][tid]; bi = coli[0][tid];
        #pragma unroll
        for (int q = 1; q < 4; ++q) {
            ov = colv[q][tid]; oi = coli[q][tid];
            if (ov > bv || (ov == bv && oi < bi)) { bv = ov; bi = oi; }
        }
        sc_s2t[tid] = bv; ix_s2t[tid] = bi;
    }
    __syncthreads();

    // ---- per-t match decision
    float cnt = 0.f, svs = 0.f;
    if (tid < 256) {
        int t = tid;
        float st2s = sc_t2s[t];
        int   i    = ix_t2s[t];
        bool msim = st2s >= 0.05f;
        int is2s = ix_s2t[i];
        int dw = (is2s & 15) - (t & 15);
        int dh = (is2s >> 4) - (t >> 4);
        bool cyc = (dw * dw + dh * dh <= 4) && (sc_s2t[i] >= 0.05f);
        float mnz = tm[t] * sm[i] *
                    ((ix_s2t[t] != 0) ? 1.f : 0.f) *
                    ((i != 0) ? 1.f : 0.f);
        float mall = (msim && cyc) ? mnz : 0.f;
        w_score[bn * T_PATCH + t] = st2s;
        w_mall[bn * T_PATCH + t]  = mall;
        w_idx[bn * T_PATCH + t]   = i;
        cnt = mall;
        svs = st2s * mall;
    }
    #pragma unroll
    for (int off = 1; off < 64; off <<= 1) {
        cnt += __shfl_xor(cnt, off, 64);
        svs += __shfl_xor(svs, off, 64);
    }
    if (tid < 256 && (tid & 63) == 0) {
        red[(tid >> 6) * 2]     = cnt;
        red[(tid >> 6) * 2 + 1] = svs;
    }
    __syncthreads();
    if (tid == 0) {
        float c = red[0] + red[2] + red[4] + red[6];
        float s = red[1] + red[3] + red[5] + red[7];
        w_savg[bn] = (c > 0.f) ? (s * (1.f / 256.f)) : 0.f;
        out[51280 + bn] = c;   // match_counts
    }
}

// ---------------- kernel 2: top-k + formatting ----------------
__global__ void final_kernel(const float* __restrict__ w_score,
                             const float* __restrict__ w_mall,
                             const float* __restrict__ w_savg,
                             const int*   __restrict__ w_idx,
                             float* __restrict__ out) {
    int b = blockIdx.x, tid = threadIdx.x;
    __shared__ float savg[32];
    __shared__ int   topid[5];
    __shared__ float topv[5];
    if (tid < 32) savg[tid] = w_savg[b * 32 + tid];
    __syncthreads();
    if (tid == 0) {
        unsigned used = 0;
        for (int k = 0; k < 5; ++k) {
            float bv = -1e30f; int bi = 0;
            for (int n = 0; n < 32; ++n) {
                if (!((used >> n) & 1u) && savg[n] > bv) { bv = savg[n]; bi = n; }
            }
            used |= (1u << bi);
            topid[k] = bi; topv[k] = bv;
        }
    }
    __syncthreads();
    if (tid < 5) {
        out[b * 5 + tid]      = (float)topid[tid];   // id_src
        out[40 + b * 5 + tid] = topv[tid];           // score_src
    }
    int t = tid;
    for (int k = 0; k < 5; ++k) {
        int bn = b * 32 + topid[k];
        float sc = w_score[bn * 256 + t];
        float ma = w_mall[bn * 256 + t];
        int   ii = w_idx[bn * 256 + t];
        int o = (b * 5 + k) * 256 + t;
        out[80 + o] = sc;                            // score_pts
        bool nz = (ma != 0.f);
        out[10320 + 2 * o]     = nz ? (float)(t & 15)  : -1.f;  // tar_pts w
        out[10320 + 2 * o + 1] = nz ? (float)(t >> 4)  : -1.f;  // tar_pts h
        out[30800 + 2 * o]     = nz ? (float)(ii & 15) : -1.f;  // src_pts w
        out[30800 + 2 * o + 1] = nz ? (float)(ii >> 4) : -1.f;  // src_pts h
    }
}

extern "C" void kernel_launch(void* const* d_in, const int* in_sizes, int n_in,
                              void* d_out, int out_size, void* d_ws, size_t ws_size,
                              hipStream_t stream) {
    const float* src_feats = (const float*)d_in[0];
    const float* tar_feat  = (const float*)d_in[1];
    const float* src_masks = (const float*)d_in[2];
    const float* tar_mask  = (const float*)d_in[3];
    float* out = (float*)d_out;

    float* ws      = (float*)d_ws;
    float* w_score = ws;                        // 65536
    float* w_mall  = w_score + 65536;           // 65536
    float* w_savg  = w_mall + 65536;            // 256
    int*   w_idx   = (int*)(w_savg + 256);      // 65536

    sim_kernel<<<N_B * N_N, 512, 0, stream>>>(src_feats, tar_feat, src_masks,
                                              tar_mask,
                                              w_score, w_mall, w_savg, w_idx, out);
    final_kernel<<<N_B, 256, 0, stream>>>(w_score, w_mall, w_savg, w_idx, out);
}

// Round 6
// 366.922 us; speedup vs baseline: 15.8603x; 1.0130x over previous
//
#include <hip/hip_runtime.h>

#define T_PATCH 256
#define C_DIM   768
#define NCH     48      // C_DIM / 16
#define N_B     8
#define N_N     32

typedef unsigned short u16;
typedef u16   u16x8  __attribute__((ext_vector_type(8)));
typedef short s16x8  __attribute__((ext_vector_type(8)));
typedef float f32x16 __attribute__((ext_vector_type(16)));

__device__ __forceinline__ unsigned rne16(unsigned u) {
    // fp32 bits -> bf16 bits, round-to-nearest-even
    return (u + 0x7fffu + ((u >> 16) & 1u)) >> 16;
}

// 3-way RNE bf16 split: x ~= h0 + h1 + h2, |h1|<=2^-8|x|, |h2|<=2^-16|x|
__device__ __forceinline__ void split3(float x, u16& o0, u16& o1, u16& o2) {
    unsigned u0 = rne16(__float_as_uint(x));
    float f0 = __uint_as_float(u0 << 16);
    float r1 = x - f0;
    unsigned u1 = rne16(__float_as_uint(r1));
    float f1 = __uint_as_float(u1 << 16);
    float r2 = r1 - f1;
    o0 = (u16)u0; o1 = (u16)u1; o2 = (u16)(__float_as_uint(r2) >> 16);
}

// ---------------- kernel 0a: pre-split tar into 3 bf16 planes (LDS-ready layout) ----
// plane layout: [b][chunk][g][t][8]  (slot index = (b*48+c)*512 + g*256 + t)
__global__ void tar_split_kernel(const float* __restrict__ tar,
                                 u16* __restrict__ tS0, u16* __restrict__ tS1,
                                 u16* __restrict__ tS2, float* __restrict__ partT) {
    int blk = blockIdx.x;            // b*48 + c
    int b = blk / NCH, c = blk - b * NCH;
    int tid = threadIdx.x;           // 0..511
    int g = tid >> 8, t = tid & 255;
    const float* tb = tar + (size_t)b * C_DIM * T_PATCH;
    float ss = 0.f;
    u16x8 v0, v1, v2;
    #pragma unroll
    for (int j = 0; j < 8; ++j) {
        float x = tb[(c * 16 + g * 8 + j) * T_PATCH + t];
        u16 a, bb, cc;
        split3(x, a, bb, cc);
        v0[j] = a; v1[j] = bb; v2[j] = cc;
        ss = fmaf(x, x, ss);
    }
    size_t off = ((size_t)blk * 512 + tid) * 8;
    *(u16x8*)(tS0 + off) = v0;
    *(u16x8*)(tS1 + off) = v1;
    *(u16x8*)(tS2 + off) = v2;
    __shared__ float sq[512];
    sq[tid] = ss;
    __syncthreads();
    if (tid < 256) partT[blk * 256 + tid] = sq[tid] + sq[tid + 256];
}

// ---------------- kernel 0b: tar inverse norms (tm folded) ----------------
__global__ void invt_kernel(const float* __restrict__ partT,
                            const float* __restrict__ tar_mask,
                            float* __restrict__ w_invT) {
    int b = blockIdx.x, t = threadIdx.x;
    float s = 0.f;
    for (int c = 0; c < NCH; ++c) s += partT[(b * NCH + c) * 256 + t];
    float tm = tar_mask[b * 256 + t];
    w_invT[b * 256 + t] = (tm != 0.f) ? 1.f / fmaxf(sqrtf(s), 1e-12f) : 0.f;
}

// ---------------- kernel 1: per-(b,n,half) GEMM + partial argmax ----------------
// grid 512 = 2 blocks per (b,n) pair -> 2 blocks/CU co-resident. Each block:
// 256 t x 128 s, full K. 8 waves, wave tile 64x64 (2x2 MFMA tiles, acc=64 AGPR).
// Round-2 lesson: launch_bounds(512,4) caps 128 regs total; spill => WRITE_SIZE blows up.
__launch_bounds__(512, 4)
__global__ void sim_kernel(const float* __restrict__ src_feats,
                           const u16* __restrict__ tS0, const u16* __restrict__ tS1,
                           const u16* __restrict__ tS2,
                           const float* __restrict__ w_invT,
                           const float* __restrict__ src_masks,
                           float* __restrict__ w_rowv, int* __restrict__ w_rowi,
                           float* __restrict__ w_s2tv, int* __restrict__ w_s2ti) {
    __shared__ __align__(16) u16 A0[2][256][8], A1[2][256][8], A2[2][256][8];  // 24 KB
    __shared__ __align__(16) u16 B0[2][128][8], B1[2][128][8], B2[2][128][8];  // 12 KB
    __shared__ float sqS[2][128];
    __shared__ float rowv[2][256]; __shared__ int rowi[2][256];
    __shared__ float colv[4][128]; __shared__ int coli[4][128];
    __shared__ float invT[256], invS[128];

    int bh = blockIdx.x;
    int bn = bh >> 1, half = bh & 1;
    int b  = bn >> 5;
    int tid = threadIdx.x;
    int lane = tid & 63, w = tid >> 6;     // 8 waves
    int wm = w >> 1, wn = w & 1;           // 4 m-groups x 2 n-groups (64x64 tile)
    int h = lane >> 5, l5 = lane & 31;
    int colB = tid & 127, gB = (tid >> 7) & 1;   // B staging slot (tid<256)

    const float* sb = src_feats + (size_t)bn * C_DIM * T_PATCH + half * 128;

    if (tid < 256) invT[tid] = w_invT[b * 256 + tid];

    f32x16 acc[2][2];
    #pragma unroll
    for (int i = 0; i < 2; ++i)
        #pragma unroll
        for (int j = 0; j < 2; ++j) acc[i][j] = (f32x16)0.0f;

    float sss = 0.f;

    for (int c = 0; c < NCH; ++c) {
        // issue loads before barrier; latency overlaps barrier wait
        float yv[8];
        if (tid < 256) {
            #pragma unroll
            for (int j = 0; j < 8; ++j)
                yv[j] = sb[(c * 16 + gB * 8 + j) * T_PATCH + colB];
        }
        size_t aoff = (((size_t)(b * NCH + c)) * 512 + tid) * 8;
        u16x8 a0v = *(const u16x8*)(tS0 + aoff);
        u16x8 a1v = *(const u16x8*)(tS1 + aoff);
        u16x8 a2v = *(const u16x8*)(tS2 + aoff);
        __syncthreads();              // previous compute finished reading LDS
        ((u16x8*)A0)[tid] = a0v;      // slot = g*256 + t = tid
        ((u16x8*)A1)[tid] = a1v;
        ((u16x8*)A2)[tid] = a2v;
        if (tid < 256) {
            u16x8 b0v, b1v, b2v;
            #pragma unroll
            for (int j = 0; j < 8; ++j) {
                u16 a, bb, cc;
                split3(yv[j], a, bb, cc);
                b0v[j] = a; b1v[j] = bb; b2v[j] = cc;
                sss = fmaf(yv[j], yv[j], sss);
            }
            ((u16x8*)B0)[tid] = b0v;  // slot = gB*128 + colB = tid
            ((u16x8*)B1)[tid] = b1v;
            ((u16x8*)B2)[tid] = b2v;
        }
        __syncthreads();              // staging visible
        // A-frag: lane -> A[m = l5][k = h*8+j]  (validated rounds 4/5)
        s16x8 a0[2], a1[2], a2[2];
        #pragma unroll
        for (int i = 0; i < 2; ++i) {
            int row = wm * 64 + i * 32 + l5;
            a0[i] = *(const s16x8*)&A0[h][row][0];
            a1[i] = *(const s16x8*)&A1[h][row][0];
            a2[i] = *(const s16x8*)&A2[h][row][0];
        }
        #pragma unroll
        for (int j = 0; j < 2; ++j) {
            int cl = wn * 64 + j * 32 + l5;
            s16x8 b0 = *(const s16x8*)&B0[h][cl][0];
            s16x8 b1 = *(const s16x8*)&B1[h][cl][0];
            s16x8 b2 = *(const s16x8*)&B2[h][cl][0];
            #pragma unroll
            for (int i = 0; i < 2; ++i) {
                acc[i][j] = __builtin_amdgcn_mfma_f32_32x32x16_bf16(a0[i], b0, acc[i][j], 0, 0, 0);
                acc[i][j] = __builtin_amdgcn_mfma_f32_32x32x16_bf16(a0[i], b1, acc[i][j], 0, 0, 0);
                acc[i][j] = __builtin_amdgcn_mfma_f32_32x32x16_bf16(a1[i], b0, acc[i][j], 0, 0, 0);
                acc[i][j] = __builtin_amdgcn_mfma_f32_32x32x16_bf16(a1[i], b1, acc[i][j], 0, 0, 0);
                acc[i][j] = __builtin_amdgcn_mfma_f32_32x32x16_bf16(a0[i], b2, acc[i][j], 0, 0, 0);
                acc[i][j] = __builtin_amdgcn_mfma_f32_32x32x16_bf16(a2[i], b0, acc[i][j], 0, 0, 0);
            }
        }
    }

    // ---- src inverse norms for this block's 128 cols (sm folded)
    __syncthreads();
    if (tid < 256) ((float*)sqS)[tid] = sss;
    __syncthreads();
    if (tid < 128) {
        float ns = sqrtf(sqS[0][tid] + sqS[1][tid]);
        float smv = src_masks[bn * 256 + half * 128 + tid];
        invS[tid] = (smv != 0.f) ? 1.f / fmaxf(ns, 1e-12f) : 0.f;
    }
    __syncthreads();

    // ---- normalize + threshold + row/col argmax
    // C/D layout: col = l5, row = (reg&3) + 8*(reg>>2) + 4*h   [m74/m101]
    float isv[2]; int sgl[2];
    #pragma unroll
    for (int j = 0; j < 2; ++j) {
        isv[j] = invS[wn * 64 + j * 32 + l5];
        sgl[j] = half * 128 + wn * 64 + j * 32 + l5;   // global s index
    }
    float cbv[2]; int cbi[2];
    #pragma unroll
    for (int j = 0; j < 2; ++j) { cbv[j] = -1.f; cbi[j] = 0; }

    #pragma unroll
    for (int i = 0; i < 2; ++i) {
        #pragma unroll
        for (int r = 0; r < 16; ++r) {
            int trow = wm * 64 + i * 32 + (r & 3) + 8 * (r >> 2) + 4 * h;
            float it = invT[trow];   // broadcast
            float v[2];
            #pragma unroll
            for (int j = 0; j < 2; ++j) {
                float x = acc[i][j][r] * it * isv[j];
                v[j] = (x >= 0.05f) ? x : 0.f;
            }
            // row candidate (j ascending = s ascending; strict > keeps first)
            float bv = -1.f; int bi = 0;
            #pragma unroll
            for (int j = 0; j < 2; ++j)
                if (v[j] > bv) { bv = v[j]; bi = sgl[j]; }
            #pragma unroll
            for (int off = 1; off < 32; off <<= 1) {
                float ov = __shfl_xor(bv, off, 64);
                int   oi = __shfl_xor(bi, off, 64);
                if (ov > bv || (ov == bv && oi < bi)) { bv = ov; bi = oi; }
            }
            if (l5 == 0) { rowv[wn][trow] = bv; rowi[wn][trow] = bi; }
            // col accumulate (trow ascending within lane)
            #pragma unroll
            for (int j = 0; j < 2; ++j)
                if (v[j] > cbv[j]) { cbv[j] = v[j]; cbi[j] = trow; }
        }
    }
    #pragma unroll
    for (int j = 0; j < 2; ++j) {
        float bv = cbv[j]; int bi = cbi[j];
        float ov = __shfl_xor(bv, 32, 64);
        int   oi = __shfl_xor(bi, 32, 64);
        if (ov > bv || (ov == bv && oi < bi)) { bv = ov; bi = oi; }
        if (h == 0) { colv[wm][wn * 64 + j * 32 + l5] = bv; coli[wm][wn * 64 + j * 32 + l5] = bi; }
    }
    __syncthreads();
    if (tid < 256) {
        float v0 = rowv[0][tid]; int i0 = rowi[0][tid];
        float v1 = rowv[1][tid]; int i1 = rowi[1][tid];
        // wn0 indices always < wn1 indices -> tie keeps wn0
        if (v1 > v0 || (v1 == v0 && i1 < i0)) { v0 = v1; i0 = i1; }
        w_rowv[bh * 256 + tid] = v0;
        w_rowi[bh * 256 + tid] = i0;
    }
    if (tid < 128) {
        float bv = colv[0][tid]; int bi = coli[0][tid];
        #pragma unroll
        for (int q = 1; q < 4; ++q) {
            float ov = colv[q][tid]; int oi = coli[q][tid];
            if (ov > bv || (ov == bv && oi < bi)) { bv = ov; bi = oi; }
        }
        w_s2tv[bn * 256 + half * 128 + tid] = bv;
        w_s2ti[bn * 256 + half * 128 + tid] = bi;
    }
}

// ---------------- kernel 2: combine halves + cycle-consistency matching ----------------
__global__ void combine_kernel(const float* __restrict__ w_rowv, const int* __restrict__ w_rowi,
                               const float* __restrict__ w_s2tv, const int* __restrict__ w_s2ti,
                               const float* __restrict__ src_masks, const float* __restrict__ tar_mask,
                               float* __restrict__ w_score, float* __restrict__ w_mall,
                               float* __restrict__ w_savg, int* __restrict__ w_idx,
                               float* __restrict__ out) {
    int bn = blockIdx.x; int b = bn >> 5; int t = threadIdx.x;
    __shared__ float sc_s2t[256]; __shared__ int ix_s2t[256];
    __shared__ float sm[256];
    __shared__ float red[8];
    sc_s2t[t] = w_s2tv[bn * 256 + t];
    ix_s2t[t] = w_s2ti[bn * 256 + t];
    sm[t]     = src_masks[bn * 256 + t];
    float v0 = w_rowv[(bn * 2) * 256 + t];     int i0 = w_rowi[(bn * 2) * 256 + t];
    float v1 = w_rowv[(bn * 2 + 1) * 256 + t]; int i1 = w_rowi[(bn * 2 + 1) * 256 + t];
    float st2s; int i;
    if (v1 > v0 || (v1 == v0 && i1 < i0)) { st2s = v1; i = i1; }
    else                                  { st2s = v0; i = i0; }
    float tmv = tar_mask[b * 256 + t];
    __syncthreads();

    bool msim = st2s >= 0.05f;
    int is2s = ix_s2t[i];
    int dw = (is2s & 15) - (t & 15);
    int dh = (is2s >> 4) - (t >> 4);
    bool cyc = (dw * dw + dh * dh <= 4) && (sc_s2t[i] >= 0.05f);
    float mnz = tmv * sm[i] *
                ((ix_s2t[t] != 0) ? 1.f : 0.f) *
                ((i != 0) ? 1.f : 0.f);
    float mall = (msim && cyc) ? mnz : 0.f;
    w_score[bn * 256 + t] = st2s;
    w_mall[bn * 256 + t]  = mall;
    w_idx[bn * 256 + t]   = i;

    float cnt = mall, svs = st2s * mall;
    #pragma unroll
    for (int off = 1; off < 64; off <<= 1) {
        cnt += __shfl_xor(cnt, off, 64);
        svs += __shfl_xor(svs, off, 64);
    }
    if ((t & 63) == 0) {
        red[(t >> 6) * 2]     = cnt;
        red[(t >> 6) * 2 + 1] = svs;
    }
    __syncthreads();
    if (t == 0) {
        float c = red[0] + red[2] + red[4] + red[6];
        float s = red[1] + red[3] + red[5] + red[7];
        w_savg[bn] = (c > 0.f) ? (s * (1.f / 256.f)) : 0.f;
        out[51280 + bn] = c;   // match_counts
    }
}

// ---------------- kernel 3: top-k + formatting ----------------
__global__ void final_kernel(const float* __restrict__ w_score,
                             const float* __restrict__ w_mall,
                             const float* __restrict__ w_savg,
                             const int*   __restrict__ w_idx,
                             float* __restrict__ out) {
    int b = blockIdx.x, tid = threadIdx.x;
    __shared__ float savg[32];
    __shared__ int   topid[5];
    __shared__ float topv[5];
    if (tid < 32) savg[tid] = w_savg[b * 32 + tid];
    __syncthreads();
    if (tid == 0) {
        unsigned used = 0;
        for (int k = 0; k < 5; ++k) {
            float bv = -1e30f; int bi = 0;
            for (int n = 0; n < 32; ++n) {
                if (!((used >> n) & 1u) && savg[n] > bv) { bv = savg[n]; bi = n; }
            }
            used |= (1u << bi);
            topid[k] = bi; topv[k] = bv;
        }
    }
    __syncthreads();
    if (tid < 5) {
        out[b * 5 + tid]      = (float)topid[tid];   // id_src
        out[40 + b * 5 + tid] = topv[tid];           // score_src
    }
    int t = tid;
    for (int k = 0; k < 5; ++k) {
        int bn = b * 32 + topid[k];
        float sc = w_score[bn * 256 + t];
        float ma = w_mall[bn * 256 + t];
        int   ii = w_idx[bn * 256 + t];
        int o = (b * 5 + k) * 256 + t;
        out[80 + o] = sc;                            // score_pts
        bool nz = (ma != 0.f);
        out[10320 + 2 * o]     = nz ? (float)(t & 15)  : -1.f;  // tar_pts w
        out[10320 + 2 * o + 1] = nz ? (float)(t >> 4)  : -1.f;  // tar_pts h
        out[30800 + 2 * o]     = nz ? (float)(ii & 15) : -1.f;  // src_pts w
        out[30800 + 2 * o + 1] = nz ? (float)(ii >> 4) : -1.f;  // src_pts h
    }
}

extern "C" void kernel_launch(void* const* d_in, const int* in_sizes, int n_in,
                              void* d_out, int out_size, void* d_ws, size_t ws_size,
                              hipStream_t stream) {
    const float* src_feats = (const float*)d_in[0];
    const float* tar_feat  = (const float*)d_in[1];
    const float* src_masks = (const float*)d_in[2];
    const float* tar_mask  = (const float*)d_in[3];
    float* out = (float*)d_out;

    // workspace layout (~12 MB)
    const size_t PLANE = (size_t)N_B * NCH * 512 * 8;   // u16 elements per plane
    u16* tS0 = (u16*)d_ws;
    u16* tS1 = tS0 + PLANE;
    u16* tS2 = tS1 + PLANE;
    float* partT  = (float*)(tS2 + PLANE);              // 8*48*256
    float* w_invT = partT + (size_t)N_B * NCH * 256;    // 2048
    float* w_rowv = w_invT + 2048;                      // 512*256
    int*   w_rowi = (int*)(w_rowv + 512 * 256);         // 512*256
    float* w_s2tv = (float*)(w_rowi + 512 * 256);       // 256*256
    int*   w_s2ti = (int*)(w_s2tv + 256 * 256);         // 256*256
    float* w_score = (float*)(w_s2ti + 256 * 256);      // 256*256
    float* w_mall  = w_score + 256 * 256;               // 256*256
    float* w_savg  = w_mall + 256 * 256;                // 256
    int*   w_idx   = (int*)(w_savg + 256);              // 256*256

    tar_split_kernel<<<N_B * NCH, 512, 0, stream>>>(tar_feat, tS0, tS1, tS2, partT);
    invt_kernel<<<N_B, 256, 0, stream>>>(partT, tar_mask, w_invT);
    sim_kernel<<<N_B * N_N * 2, 512, 0, stream>>>(src_feats, tS0, tS1, tS2, w_invT,
                                                  src_masks,
                                                  w_rowv, w_rowi, w_s2tv, w_s2ti);
    combine_kernel<<<N_B * N_N, 256, 0, stream>>>(w_rowv, w_rowi, w_s2tv, w_s2ti,
                                                  src_masks, tar_mask,
                                                  w_score, w_mall, w_savg, w_idx, out);
    final_kernel<<<N_B, 256, 0, stream>>>(w_score, w_mall, w_savg, w_idx, out);
}